// Round 2
// baseline (559.605 us; speedup 1.0000x reference)
//
#include <hip/hip_runtime.h>
#include <hip/hip_bf16.h>

typedef __bf16 bf16;
typedef __bf16 bf16x8 __attribute__((ext_vector_type(8)));
typedef float  f32x4  __attribute__((ext_vector_type(4)));

#define NB 2
#define NS 2048
#define NE 1024
#define NH 16
#define ND 64
#define NC 256

// ---------------------------------------------------------------------------
// f32 -> bf16 conversion (vectorized, 8 elems/thread)
// ---------------------------------------------------------------------------
__global__ __launch_bounds__(256) void cvt_kernel(
    const float* __restrict__ src, bf16* __restrict__ dst, int n) {
  int i = (blockIdx.x * 256 + threadIdx.x) * 8;
  if (i >= n) return;
  float4 a = ((const float4*)(src + i))[0];
  float4 b = ((const float4*)(src + i))[1];
  bf16x8 o;
  o[0] = (bf16)a.x; o[1] = (bf16)a.y; o[2] = (bf16)a.z; o[3] = (bf16)a.w;
  o[4] = (bf16)b.x; o[5] = (bf16)b.y; o[6] = (bf16)b.z; o[7] = (bf16)b.w;
  *(bf16x8*)(dst + i) = o;
}

// ---------------------------------------------------------------------------
// mod = silu(conditioning) @ Wc^T + bc   -> f32 (B, 2E)   (all f32 inputs)
// ---------------------------------------------------------------------------
__global__ __launch_bounds__(256) void mod_kernel(
    const float* __restrict__ cond, const float* __restrict__ Wc,
    const float* __restrict__ bc, float* __restrict__ mod) {
  __shared__ float scond[NC];
  int b  = blockIdx.x >> 3;          // 8 blocks per batch (2048/256)
  int j0 = (blockIdx.x & 7) * 256;
  float c = cond[b * NC + threadIdx.x];
  scond[threadIdx.x] = c / (1.f + __expf(-c));
  __syncthreads();
  int j = j0 + threadIdx.x;
  float acc = bc[j];
  const float* wrow = Wc + (size_t)j * NC;
  for (int cc = 0; cc < NC; ++cc) acc += scond[cc] * wrow[cc];
  mod[b * 2 * NE + j] = acc;
}

// ---------------------------------------------------------------------------
// GEMM NT: C[m][n] = sum_k A[m][k] * Bw[n][k]   (A, Bw bf16)
// mode 0: out bf16, layout (B,H,S,D)   [Q, K]
// mode 1: out bf16, layout (B,H,D,S)   [V transposed]
// mode 2: out f32, row-major (M,N)     [O-projection]
// block = 256 (4 waves); per block 64(M) x 64(N); wave w -> 16 rows.
// ---------------------------------------------------------------------------
__global__ __launch_bounds__(256) void gemm_nt(
    const bf16* __restrict__ A, const bf16* __restrict__ Bw,
    void* __restrict__ out, int M, int N, int K, int mode) {
  int l  = threadIdx.x & 63;
  int w  = threadIdx.x >> 6;
  int lr = l & 15;       // fragment row within 16
  int lg = l >> 4;       // k-group (0..3)
  int m0 = blockIdx.x * 64 + w * 16;
  int n0 = blockIdx.y * 64;

  f32x4 acc[4];
#pragma unroll
  for (int nt = 0; nt < 4; ++nt) acc[nt] = (f32x4){0.f, 0.f, 0.f, 0.f};

  const bf16* arow = A + (size_t)(m0 + lr) * K + lg * 8;
  const bf16* brow[4];
#pragma unroll
  for (int nt = 0; nt < 4; ++nt)
    brow[nt] = Bw + (size_t)(n0 + nt * 16 + lr) * K + lg * 8;

  for (int k0 = 0; k0 < K; k0 += 32) {
    bf16x8 a = *(const bf16x8*)(arow + k0);
#pragma unroll
    for (int nt = 0; nt < 4; ++nt) {
      bf16x8 bf = *(const bf16x8*)(brow[nt] + k0);
      acc[nt] = __builtin_amdgcn_mfma_f32_16x16x32_bf16(a, bf, acc[nt], 0, 0, 0);
    }
  }

#pragma unroll
  for (int nt = 0; nt < 4; ++nt) {
#pragma unroll
    for (int r = 0; r < 4; ++r) {
      int row = m0 + lg * 4 + r;         // M index
      int col = n0 + nt * 16 + lr;       // N index
      float v = acc[nt][r];
      if (mode == 2) {
        ((float*)out)[(size_t)row * N + col] = v;
      } else {
        int b = row >> 11, s = row & 2047;
        int h = col >> 6,  d = col & 63;
        size_t idx;
        if (mode == 0) idx = (((size_t)(b * NH + h)) * NS + s) * ND + d;
        else           idx = (((size_t)(b * NH + h)) * ND + d) * NS + s;
        ((bf16*)out)[idx] = (bf16)v;
      }
    }
  }
}

// ---------------------------------------------------------------------------
// Flash attention, causal. Q,K in (B,H,S,D), V in (B,H,D,S). Out (B,S,E) bf16.
// block = 256 (4 waves); each wave owns 16 q-rows; KV tile = 32.
// ---------------------------------------------------------------------------
__global__ __launch_bounds__(256) void attn_kernel(
    const bf16* __restrict__ Q, const bf16* __restrict__ Km,
    const bf16* __restrict__ Vt, bf16* __restrict__ O) {
  __shared__ bf16 pbuf[4][16][32];
  int l  = threadIdx.x & 63;
  int w  = threadIdx.x >> 6;
  int lr = l & 15;
  int lg = l >> 4;
  int bh = blockIdx.y;                 // 0..31
  int b = bh >> 4, h = bh & 15;
  int qbase = blockIdx.x * 64 + w * 16;

  const bf16* Qb = Q  + (size_t)bh * NS * ND;
  const bf16* Kb = Km + (size_t)bh * NS * ND;
  const bf16* Vb = Vt + (size_t)bh * ND * NS;

  bf16x8 qf0 = *(const bf16x8*)(Qb + (size_t)(qbase + lr) * ND + lg * 8);
  bf16x8 qf1 = *(const bf16x8*)(Qb + (size_t)(qbase + lr) * ND + 32 + lg * 8);

  f32x4 o[4];
#pragma unroll
  for (int nt = 0; nt < 4; ++nt) o[nt] = (f32x4){0.f, 0.f, 0.f, 0.f};
  float mrow[4], lsum[4];
#pragma unroll
  for (int r = 0; r < 4; ++r) { mrow[r] = -1e30f; lsum[r] = 0.f; }

  const float scale = 0.125f;   // 64^-0.5

  for (int kv0 = 0; kv0 < qbase + 16; kv0 += 32) {
    f32x4 sa[2];
#pragma unroll
    for (int t = 0; t < 2; ++t) {
      sa[t] = (f32x4){0.f, 0.f, 0.f, 0.f};
      const bf16* krow = Kb + (size_t)(kv0 + t * 16 + lr) * ND + lg * 8;
      bf16x8 k0 = *(const bf16x8*)(krow);
      bf16x8 k1 = *(const bf16x8*)(krow + 32);
      sa[t] = __builtin_amdgcn_mfma_f32_16x16x32_bf16(qf0, k0, sa[t], 0, 0, 0);
      sa[t] = __builtin_amdgcn_mfma_f32_16x16x32_bf16(qf1, k1, sa[t], 0, 0, 0);
    }
    float p0[4], p1[4], pmax[4];
#pragma unroll
    for (int r = 0; r < 4; ++r) {
      int qi = qbase + lg * 4 + r;
      p0[r] = (kv0 + lr      > qi) ? -1e30f : sa[0][r] * scale;
      p1[r] = (kv0 + 16 + lr > qi) ? -1e30f : sa[1][r] * scale;
      pmax[r] = fmaxf(p0[r], p1[r]);
    }
#pragma unroll
    for (int mk = 1; mk <= 8; mk <<= 1)
#pragma unroll
      for (int r = 0; r < 4; ++r)
        pmax[r] = fmaxf(pmax[r], __shfl_xor(pmax[r], mk, 64));
    float alpha[4], rsum[4];
#pragma unroll
    for (int r = 0; r < 4; ++r) {
      float nm = fmaxf(mrow[r], pmax[r]);
      alpha[r] = __expf(mrow[r] - nm);
      mrow[r] = nm;
      p0[r] = __expf(p0[r] - nm);
      p1[r] = __expf(p1[r] - nm);
      rsum[r] = p0[r] + p1[r];
    }
#pragma unroll
    for (int mk = 1; mk <= 8; mk <<= 1)
#pragma unroll
      for (int r = 0; r < 4; ++r)
        rsum[r] += __shfl_xor(rsum[r], mk, 64);
#pragma unroll
    for (int r = 0; r < 4; ++r) lsum[r] = lsum[r] * alpha[r] + rsum[r];
#pragma unroll
    for (int nt = 0; nt < 4; ++nt)
#pragma unroll
      for (int r = 0; r < 4; ++r) o[nt][r] *= alpha[r];

    // transpose P through LDS (wave-private buffer)
#pragma unroll
    for (int r = 0; r < 4; ++r) {
      pbuf[w][lg * 4 + r][lr]      = (bf16)p0[r];
      pbuf[w][lg * 4 + r][16 + lr] = (bf16)p1[r];
    }
    asm volatile("s_waitcnt lgkmcnt(0)" ::: "memory");
    __builtin_amdgcn_sched_barrier(0);
    bf16x8 pa = *(const bf16x8*)(&pbuf[w][lr][lg * 8]);
#pragma unroll
    for (int nt = 0; nt < 4; ++nt) {
      bf16x8 vf = *(const bf16x8*)(Vb + (size_t)(nt * 16 + lr) * NS + kv0 + lg * 8);
      o[nt] = __builtin_amdgcn_mfma_f32_16x16x32_bf16(pa, vf, o[nt], 0, 0, 0);
    }
    asm volatile("s_waitcnt lgkmcnt(0)" ::: "memory");
    __builtin_amdgcn_sched_barrier(0);
  }

#pragma unroll
  for (int nt = 0; nt < 4; ++nt)
#pragma unroll
    for (int r = 0; r < 4; ++r) {
      int qi = qbase + lg * 4 + r;
      int d  = nt * 16 + lr;
      O[((size_t)(b * NS) + qi) * NE + h * ND + d] = (bf16)(o[nt][r] / lsum[r]);
    }
}

// ---------------------------------------------------------------------------
// RMSNorm + FiLM: one block per row of tmp (f32), write f32 out
// ---------------------------------------------------------------------------
__global__ __launch_bounds__(256) void norm_kernel(
    const float* __restrict__ tmp, const float* __restrict__ rms_scale,
    const float* __restrict__ mod, float* __restrict__ out) {
  int row = blockIdx.x;
  int b = row >> 11;
  const float* trow = tmp + (size_t)row * NE;
  float4 v = ((const float4*)trow)[threadIdx.x];
  float vv[4] = {v.x, v.y, v.z, v.w};
  float ss = vv[0]*vv[0] + vv[1]*vv[1] + vv[2]*vv[2] + vv[3]*vv[3];
#pragma unroll
  for (int mk = 1; mk < 64; mk <<= 1) ss += __shfl_xor(ss, mk, 64);
  __shared__ float sred[4];
  if ((threadIdx.x & 63) == 0) sred[threadIdx.x >> 6] = ss;
  __syncthreads();
  float tot = sred[0] + sred[1] + sred[2] + sred[3];
  float rinv = rsqrtf(tot * (1.f / NE) + 1e-6f);
  const float* modb = mod + b * 2 * NE;
#pragma unroll
  for (int j = 0; j < 4; ++j) {
    int e = threadIdx.x * 4 + j;
    float xn = vv[j] * rinv * rms_scale[e];
    xn = xn * (1.f + modb[NE + e]) + modb[e];
    out[(size_t)row * NE + e] = xn;
  }
}

// ---------------------------------------------------------------------------
extern "C" void kernel_launch(void* const* d_in, const int* in_sizes, int n_in,
                              void* d_out, int out_size, void* d_ws, size_t ws_size,
                              hipStream_t stream) {
  const float* x    = (const float*)d_in[0];
  // d_in[1] = mask (causal triu) -- known analytically, ignored
  const float* cond = (const float*)d_in[2];
  const float* Wq   = (const float*)d_in[3];
  const float* Wk   = (const float*)d_in[4];
  const float* Wv   = (const float*)d_in[5];
  const float* Wo   = (const float*)d_in[6];
  const float* rmss = (const float*)d_in[7];
  const float* Wc   = (const float*)d_in[8];
  const float* bc   = (const float*)d_in[9];
  float* out = (float*)d_out;

  char* ws = (char*)d_ws;
  const size_t MB = 1u << 20;
  bf16*  xb  = (bf16*)(ws);               // 0..8MB    (B,S,E) bf16
  bf16*  Wqb = (bf16*)(ws + 8  * MB);     // 8..10MB
  bf16*  Wkb = (bf16*)(ws + 10 * MB);     // 10..12MB
  bf16*  Wvb = (bf16*)(ws + 12 * MB);     // 12..14MB
  bf16*  Wob = (bf16*)(ws + 14 * MB);     // 14..16MB
  bf16*  Qb  = (bf16*)(ws + 16 * MB);     // 16..24MB  (B,H,S,D)
  bf16*  Kb  = (bf16*)(ws + 24 * MB);     // 24..32MB  (B,H,S,D)
  bf16*  Vt  = (bf16*)(ws + 32 * MB);     // 32..40MB  (B,H,D,S)
  bf16*  Oa  = (bf16*)(ws);               // reuse 0..8MB (x dead after V gemm)
  float* tmp = (float*)(ws + 16 * MB);    // reuse 16..32MB (Q,K dead after attn)
  float* mod = (float*)(ws + 40 * MB);    // 40MB + 16KB

  const int NX = NB * NS * NE;   // 4194304
  const int NW = NE * NE;        // 1048576

  mod_kernel<<<16, 256, 0, stream>>>(cond, Wc, bc, mod);

  cvt_kernel<<<NX / 2048, 256, 0, stream>>>(x,  xb,  NX);
  cvt_kernel<<<NW / 2048, 256, 0, stream>>>(Wq, Wqb, NW);
  cvt_kernel<<<NW / 2048, 256, 0, stream>>>(Wk, Wkb, NW);
  cvt_kernel<<<NW / 2048, 256, 0, stream>>>(Wv, Wvb, NW);
  cvt_kernel<<<NW / 2048, 256, 0, stream>>>(Wo, Wob, NW);

  dim3 g(64, 16);
  gemm_nt<<<g, 256, 0, stream>>>(xb, Wqb, Qb, NB * NS, NE, NE, 0);
  gemm_nt<<<g, 256, 0, stream>>>(xb, Wkb, Kb, NB * NS, NE, NE, 0);
  gemm_nt<<<g, 256, 0, stream>>>(xb, Wvb, Vt, NB * NS, NE, NE, 1);

  attn_kernel<<<dim3(32, 32), 256, 0, stream>>>(Qb, Kb, Vt, Oa);

  gemm_nt<<<g, 256, 0, stream>>>(Oa, Wob, tmp, NB * NS, NE, NE, 2);

  norm_kernel<<<NB * NS, 256, 0, stream>>>(tmp, rmss, mod, out);
}

// Round 3
// 233.774 us; speedup vs baseline: 2.3938x; 2.3938x over previous
//
#include <hip/hip_runtime.h>
#include <hip/hip_bf16.h>
#include <stdint.h>

typedef __bf16 bf16;
typedef __bf16 bf16x8 __attribute__((ext_vector_type(8)));
typedef float  f32x4  __attribute__((ext_vector_type(4)));

#define NB 2
#define NS 2048
#define NE 1024
#define NH 16
#define ND 64
#define NC 256

// async global->LDS, 16B per lane, wave-uniform LDS base + lane*16
__device__ __forceinline__ void gload16(void* lds, const void* g) {
  __builtin_amdgcn_global_load_lds(
      (const __attribute__((address_space(1))) void*)g,
      (__attribute__((address_space(3))) void*)lds, 16, 0, 0);
}

// ---------------------------------------------------------------------------
// f32 -> bf16 conversion (vectorized, 8 elems/thread)
// ---------------------------------------------------------------------------
__global__ __launch_bounds__(256) void cvt_kernel(
    const float* __restrict__ src, bf16* __restrict__ dst, int n) {
  int i = (blockIdx.x * 256 + threadIdx.x) * 8;
  if (i >= n) return;
  float4 a = ((const float4*)(src + i))[0];
  float4 b = ((const float4*)(src + i))[1];
  bf16x8 o;
  o[0] = (bf16)a.x; o[1] = (bf16)a.y; o[2] = (bf16)a.z; o[3] = (bf16)a.w;
  o[4] = (bf16)b.x; o[5] = (bf16)b.y; o[6] = (bf16)b.z; o[7] = (bf16)b.w;
  *(bf16x8*)(dst + i) = o;
}

// ---------------------------------------------------------------------------
// mod = silu(conditioning) @ Wc^T + bc   -> f32 (B, 2E)
// ---------------------------------------------------------------------------
__global__ __launch_bounds__(256) void mod_kernel(
    const float* __restrict__ cond, const float* __restrict__ Wc,
    const float* __restrict__ bc, float* __restrict__ mod) {
  __shared__ float scond[NC];
  int b  = blockIdx.x >> 3;
  int j0 = (blockIdx.x & 7) * 256;
  float c = cond[b * NC + threadIdx.x];
  scond[threadIdx.x] = c / (1.f + __expf(-c));
  __syncthreads();
  int j = j0 + threadIdx.x;
  float acc = bc[j];
  const float* wrow = Wc + (size_t)j * NC;
  for (int cc = 0; cc < NC; ++cc) acc += scond[cc] * wrow[cc];
  mod[b * 2 * NE + j] = acc;
}

// ---------------------------------------------------------------------------
// 128x128 LDS-staged NT GEMM (m97 structure). K multiple of 32.
// MODE 0: fused QKV. out = Qb base; K at +4M elems, V^T at +8M elems.
//         grid.y covers N=3072 (W selected by n>>10).
// MODE 1: O-projection, f32 row-major out, N=1024.
// ---------------------------------------------------------------------------
template<int MODE>
__global__ __launch_bounds__(256) void gemm128(
    const bf16* __restrict__ A, const bf16* __restrict__ W0,
    const bf16* __restrict__ W1, const bf16* __restrict__ W2,
    void* __restrict__ out, int K) {
  __shared__ bf16 As[128 * 32];
  __shared__ bf16 Bs[128 * 32];
  const int t = threadIdx.x, w = t >> 6, l = t & 63;
  const int lr = l & 15, lg = l >> 4;
  const int wm = w >> 1, wn = w & 1;
  const int m0 = blockIdx.x * 128;
  const int ng = blockIdx.y * 128;

  const bf16* Bw;
  if (MODE == 0) {
    const bf16* Ws[3] = {W0, W1, W2};
    Bw = Ws[ng >> 10] + (size_t)(ng & 1023) * K;
  } else {
    Bw = W0 + (size_t)ng * K;
  }

  f32x4 acc[4][4];
#pragma unroll
  for (int i = 0; i < 4; ++i)
#pragma unroll
    for (int j = 0; j < 4; ++j) acc[i][j] = (f32x4){0.f, 0.f, 0.f, 0.f};

  // staging: 8 chunks of 1KB each for A and B; wave w owns chunks {2w, 2w+1}
  const int srow = (l >> 2);          // 0..15 within chunk
  const int scol = (l & 3) * 8;       // 0,8,16,24

  for (int kt = 0; kt < K; kt += 32) {
#pragma unroll
    for (int r = 0; r < 2; ++r) {
      int cc = w * 2 + r;
      int row = cc * 16 + srow;
      gload16((char*)As + cc * 1024, A  + (size_t)(m0 + row) * K + kt + scol);
      gload16((char*)Bs + cc * 1024, Bw + (size_t)row        * K + kt + scol);
    }
    __syncthreads();   // drains vmcnt before barrier (compiler-emitted)
    bf16x8 af[4], bfr[4];
#pragma unroll
    for (int i = 0; i < 4; ++i) {
      af[i]  = *(const bf16x8*)(As + (wm * 64 + i * 16 + lr) * 32 + lg * 8);
      bfr[i] = *(const bf16x8*)(Bs + (wn * 64 + i * 16 + lr) * 32 + lg * 8);
    }
#pragma unroll
    for (int i = 0; i < 4; ++i)
#pragma unroll
      for (int j = 0; j < 4; ++j)
        acc[i][j] = __builtin_amdgcn_mfma_f32_16x16x32_bf16(af[i], bfr[j], acc[i][j], 0, 0, 0);
    if (kt + 32 < K) __syncthreads();
  }

#pragma unroll
  for (int i = 0; i < 4; ++i) {
#pragma unroll
    for (int j = 0; j < 4; ++j) {
#pragma unroll
      for (int r = 0; r < 4; ++r) {
        int row = m0 + wm * 64 + i * 16 + lg * 4 + r;
        int col = ng + wn * 64 + j * 16 + lr;
        float v = acc[i][j][r];
        if (MODE == 1) {
          ((float*)out)[(size_t)row * NE + col] = v;
        } else {
          int b = row >> 11, s = row & 2047;
          int wi = col >> 10, nc = col & 1023;
          int h = nc >> 6, d = nc & 63;
          size_t idx;
          if (wi == 2)  // V^T: (B,H,D,S)
            idx = 8388608u + (((size_t)(b * NH + h)) * ND + d) * NS + s;
          else          // Q or K: (B,H,S,D)
            idx = (size_t)wi * 4194304u + (((size_t)(b * NH + h)) * NS + s) * ND + d;
          ((bf16*)out)[idx] = (bf16)v;
        }
      }
    }
  }
}

// ---------------------------------------------------------------------------
// Flash attention, causal. Q,K (B,H,S,D), V^T (B,H,D,S). Out (B,S,E) bf16.
// 4 waves/block, 32 q-rows/wave (128 q/block), kv tile = 64.
// ---------------------------------------------------------------------------
__global__ __launch_bounds__(256) void attn_kernel(
    const bf16* __restrict__ Q, const bf16* __restrict__ Km,
    const bf16* __restrict__ Vt, bf16* __restrict__ O) {
  __shared__ bf16 pbuf[4][32][72];   // +8 pad: row stride 144B -> 2-way (free)
  const int l = threadIdx.x & 63, w = threadIdx.x >> 6;
  const int lr = l & 15, lg = l >> 4;
  const int bh = blockIdx.y, b = bh >> 4, h = bh & 15;
  const int qt = (int)gridDim.x - 1 - (int)blockIdx.x;  // heavy tiles first
  const int qbase = qt * 128 + w * 32;

  const bf16* Qb = Q  + (size_t)bh * NS * ND;
  const bf16* Kb = Km + (size_t)bh * NS * ND;
  const bf16* Vb = Vt + (size_t)bh * ND * NS;

  bf16x8 qf[2][2];
#pragma unroll
  for (int mt = 0; mt < 2; ++mt)
#pragma unroll
    for (int kh = 0; kh < 2; ++kh)
      qf[mt][kh] = *(const bf16x8*)(Qb + (size_t)(qbase + mt * 16 + lr) * ND + kh * 32 + lg * 8);

  f32x4 o[2][4];
  float mrow[2][4], lsum[2][4];
  int qr[2][4];
#pragma unroll
  for (int mt = 0; mt < 2; ++mt)
#pragma unroll
    for (int r = 0; r < 4; ++r) {
      mrow[mt][r] = -1e30f; lsum[mt][r] = 0.f;
      qr[mt][r] = qbase + mt * 16 + lg * 4 + r;
      if (r == 0) { o[mt][0] = (f32x4){0,0,0,0}; o[mt][1] = (f32x4){0,0,0,0};
                    o[mt][2] = (f32x4){0,0,0,0}; o[mt][3] = (f32x4){0,0,0,0}; }
    }

  const float c = 0.125f * 1.44269504089f;   // scale * log2(e)

  for (int kv0 = 0; kv0 < qbase + 32; kv0 += 64) {
    // ---- QK^T ----
    f32x4 s[2][4];
#pragma unroll
    for (int nt = 0; nt < 4; ++nt) {
      const bf16* kr = Kb + (size_t)(kv0 + nt * 16 + lr) * ND + lg * 8;
      bf16x8 k0 = *(const bf16x8*)kr;
      bf16x8 k1 = *(const bf16x8*)(kr + 32);
#pragma unroll
      for (int mt = 0; mt < 2; ++mt) {
        f32x4 z = (f32x4){0.f, 0.f, 0.f, 0.f};
        z = __builtin_amdgcn_mfma_f32_16x16x32_bf16(qf[mt][0], k0, z, 0, 0, 0);
        z = __builtin_amdgcn_mfma_f32_16x16x32_bf16(qf[mt][1], k1, z, 0, 0, 0);
        s[mt][nt] = z;
      }
    }
    // ---- scale + causal mask + row max ----
    const bool edge = (kv0 + 63 > qbase);
    float pm[2][4];
#pragma unroll
    for (int mt = 0; mt < 2; ++mt)
#pragma unroll
      for (int r = 0; r < 4; ++r) pm[mt][r] = -1e30f;
#pragma unroll
    for (int mt = 0; mt < 2; ++mt)
#pragma unroll
      for (int nt = 0; nt < 4; ++nt) {
        f32x4 v = s[mt][nt] * c;
#pragma unroll
        for (int r = 0; r < 4; ++r) {
          if (edge && (kv0 + nt * 16 + lr > qr[mt][r])) v[r] = -1e30f;
          pm[mt][r] = fmaxf(pm[mt][r], v[r]);
        }
        s[mt][nt] = v;
      }
#pragma unroll
    for (int mk = 1; mk <= 8; mk <<= 1)
#pragma unroll
      for (int mt = 0; mt < 2; ++mt)
#pragma unroll
        for (int r = 0; r < 4; ++r)
          pm[mt][r] = fmaxf(pm[mt][r], __shfl_xor(pm[mt][r], mk, 64));
    // ---- online softmax ----
    float al[2][4], rs[2][4];
#pragma unroll
    for (int mt = 0; mt < 2; ++mt)
#pragma unroll
      for (int r = 0; r < 4; ++r) {
        float nm = fmaxf(mrow[mt][r], pm[mt][r]);
        al[mt][r] = exp2f(mrow[mt][r] - nm);
        mrow[mt][r] = nm;
        rs[mt][r] = 0.f;
      }
#pragma unroll
    for (int mt = 0; mt < 2; ++mt)
#pragma unroll
      for (int nt = 0; nt < 4; ++nt)
#pragma unroll
        for (int r = 0; r < 4; ++r) {
          float p = exp2f(s[mt][nt][r] - mrow[mt][r]);
          s[mt][nt][r] = p;
          rs[mt][r] += p;
        }
#pragma unroll
    for (int mk = 1; mk <= 8; mk <<= 1)
#pragma unroll
      for (int mt = 0; mt < 2; ++mt)
#pragma unroll
        for (int r = 0; r < 4; ++r)
          rs[mt][r] += __shfl_xor(rs[mt][r], mk, 64);
#pragma unroll
    for (int mt = 0; mt < 2; ++mt)
#pragma unroll
      for (int r = 0; r < 4; ++r)
        lsum[mt][r] = lsum[mt][r] * al[mt][r] + rs[mt][r];
#pragma unroll
    for (int mt = 0; mt < 2; ++mt)
#pragma unroll
      for (int dt = 0; dt < 4; ++dt)
#pragma unroll
        for (int r = 0; r < 4; ++r) o[mt][dt][r] *= al[mt][r];
    // ---- P transpose through (wave-private, padded) LDS ----
#pragma unroll
    for (int mt = 0; mt < 2; ++mt)
#pragma unroll
      for (int nt = 0; nt < 4; ++nt)
#pragma unroll
        for (int r = 0; r < 4; ++r)
          pbuf[w][mt * 16 + lg * 4 + r][nt * 16 + lr] = (bf16)s[mt][nt][r];
    asm volatile("s_waitcnt lgkmcnt(0)" ::: "memory");
    __builtin_amdgcn_sched_barrier(0);
    bf16x8 pa[2][2];
#pragma unroll
    for (int mt = 0; mt < 2; ++mt)
#pragma unroll
      for (int ks = 0; ks < 2; ++ks)
        pa[mt][ks] = *(const bf16x8*)(&pbuf[w][mt * 16 + lr][ks * 32 + lg * 8]);
    // ---- PV ----
#pragma unroll
    for (int dt = 0; dt < 4; ++dt) {
      const bf16* vr = Vb + (size_t)(dt * 16 + lr) * NS + kv0 + lg * 8;
      bf16x8 v0 = *(const bf16x8*)vr;
      bf16x8 v1 = *(const bf16x8*)(vr + 32);
#pragma unroll
      for (int mt = 0; mt < 2; ++mt) {
        o[mt][dt] = __builtin_amdgcn_mfma_f32_16x16x32_bf16(pa[mt][0], v0, o[mt][dt], 0, 0, 0);
        o[mt][dt] = __builtin_amdgcn_mfma_f32_16x16x32_bf16(pa[mt][1], v1, o[mt][dt], 0, 0, 0);
      }
    }
    __builtin_amdgcn_sched_barrier(0);
  }

#pragma unroll
  for (int mt = 0; mt < 2; ++mt) {
    float rl[4];
#pragma unroll
    for (int r = 0; r < 4; ++r) rl[r] = 1.f / lsum[mt][r];
#pragma unroll
    for (int dt = 0; dt < 4; ++dt)
#pragma unroll
      for (int r = 0; r < 4; ++r)
        O[((size_t)(b * NS) + qr[mt][r]) * NE + h * ND + dt * 16 + lr] =
            (bf16)(o[mt][dt][r] * rl[r]);
  }
}

// ---------------------------------------------------------------------------
// RMSNorm + FiLM
// ---------------------------------------------------------------------------
__global__ __launch_bounds__(256) void norm_kernel(
    const float* __restrict__ tmp, const float* __restrict__ rms_scale,
    const float* __restrict__ mod, float* __restrict__ out) {
  int row = blockIdx.x;
  int b = row >> 11;
  const float* trow = tmp + (size_t)row * NE;
  float4 v = ((const float4*)trow)[threadIdx.x];
  float vv[4] = {v.x, v.y, v.z, v.w};
  float ss = vv[0]*vv[0] + vv[1]*vv[1] + vv[2]*vv[2] + vv[3]*vv[3];
#pragma unroll
  for (int mk = 1; mk < 64; mk <<= 1) ss += __shfl_xor(ss, mk, 64);
  __shared__ float sred[4];
  if ((threadIdx.x & 63) == 0) sred[threadIdx.x >> 6] = ss;
  __syncthreads();
  float tot = sred[0] + sred[1] + sred[2] + sred[3];
  float rinv = rsqrtf(tot * (1.f / NE) + 1e-6f);
  const float* modb = mod + b * 2 * NE;
#pragma unroll
  for (int j = 0; j < 4; ++j) {
    int e = threadIdx.x * 4 + j;
    float xn = vv[j] * rinv * rms_scale[e];
    xn = xn * (1.f + modb[NE + e]) + modb[e];
    out[(size_t)row * NE + e] = xn;
  }
}

// ---------------------------------------------------------------------------
extern "C" void kernel_launch(void* const* d_in, const int* in_sizes, int n_in,
                              void* d_out, int out_size, void* d_ws, size_t ws_size,
                              hipStream_t stream) {
  const float* x    = (const float*)d_in[0];
  const float* cond = (const float*)d_in[2];
  const float* Wq   = (const float*)d_in[3];
  const float* Wk   = (const float*)d_in[4];
  const float* Wv   = (const float*)d_in[5];
  const float* Wo   = (const float*)d_in[6];
  const float* rmss = (const float*)d_in[7];
  const float* Wc   = (const float*)d_in[8];
  const float* bc   = (const float*)d_in[9];
  float* out = (float*)d_out;

  char* ws = (char*)d_ws;
  const size_t MB = 1u << 20;
  bf16*  xb  = (bf16*)(ws);               // 0..8MB    (B,S,E) bf16
  bf16*  Wqb = (bf16*)(ws + 8  * MB);
  bf16*  Wkb = (bf16*)(ws + 10 * MB);
  bf16*  Wvb = (bf16*)(ws + 12 * MB);
  bf16*  Wob = (bf16*)(ws + 14 * MB);
  bf16*  Qb  = (bf16*)(ws + 16 * MB);     // (B,H,S,D); K at +4M el; V^T at +8M el
  bf16*  Vt  = (bf16*)(ws + 32 * MB);
  bf16*  Kb  = (bf16*)(ws + 24 * MB);
  bf16*  Oa  = (bf16*)(ws);               // reuse x region
  float* tmp = (float*)(ws + 16 * MB);    // reuse Q/K region
  float* mod = (float*)(ws + 40 * MB);

  const int NX = NB * NS * NE;
  const int NW = NE * NE;

  mod_kernel<<<16, 256, 0, stream>>>(cond, Wc, bc, mod);

  cvt_kernel<<<NX / 2048, 256, 0, stream>>>(x,  xb,  NX);
  cvt_kernel<<<NW / 2048, 256, 0, stream>>>(Wq, Wqb, NW);
  cvt_kernel<<<NW / 2048, 256, 0, stream>>>(Wk, Wkb, NW);
  cvt_kernel<<<NW / 2048, 256, 0, stream>>>(Wv, Wvb, NW);
  cvt_kernel<<<NW / 2048, 256, 0, stream>>>(Wo, Wob, NW);

  // fused QKV projection: N = 3072
  gemm128<0><<<dim3(32, 24), 256, 0, stream>>>(xb, Wqb, Wkb, Wvb, Qb, NE);

  attn_kernel<<<dim3(16, 32), 256, 0, stream>>>(Qb, Kb, Vt, Oa);

  // O projection -> f32 tmp
  gemm128<1><<<dim3(32, 8), 256, 0, stream>>>(Oa, Wob, nullptr, nullptr, tmp, NE);

  norm_kernel<<<NB * NS, 256, 0, stream>>>(tmp, rmss, mod, out);
}

// Round 5
// 209.455 us; speedup vs baseline: 2.6717x; 1.1161x over previous
//
#include <hip/hip_runtime.h>
#include <hip/hip_bf16.h>
#include <stdint.h>

typedef __bf16 bf16;
typedef __bf16 bf16x8 __attribute__((ext_vector_type(8)));
typedef float  f32x4  __attribute__((ext_vector_type(4)));

#define NB 2
#define NS 2048
#define NE 1024
#define NH 16
#define ND 64
#define NC 256

// async global->LDS, 16B per lane, wave-uniform LDS base + lane*16
__device__ __forceinline__ void gload16(void* lds, const void* g) {
  __builtin_amdgcn_global_load_lds(
      (const __attribute__((address_space(1))) void*)g,
      (__attribute__((address_space(3))) void*)lds, 16, 0, 0);
}

// max over the 16-lane group (lanes sharing lane>>4) via DPP row_ror
__device__ __forceinline__ float dppmax(float x, int imm) {
  // imm must be literal at each call site via template below
  return x;
}

template <int CTRL>
__device__ __forceinline__ float rowror_max(float x) {
  int xi = __builtin_bit_cast(int, x);
  int yi = __builtin_amdgcn_update_dpp(xi, xi, CTRL, 0xF, 0xF, false);
  return fmaxf(x, __builtin_bit_cast(float, yi));
}

__device__ __forceinline__ float rowmax16(float x) {
  x = rowror_max<0x121>(x);   // row_ror:1
  x = rowror_max<0x122>(x);   // row_ror:2
  x = rowror_max<0x124>(x);   // row_ror:4
  x = rowror_max<0x128>(x);   // row_ror:8
  return x;
}

// ---------------------------------------------------------------------------
// f32 -> bf16 conversion (vectorized, 8 elems/thread)
// ---------------------------------------------------------------------------
__global__ __launch_bounds__(256) void cvt_kernel(
    const float* __restrict__ src, bf16* __restrict__ dst, int n) {
  int i = (blockIdx.x * 256 + threadIdx.x) * 8;
  if (i >= n) return;
  float4 a = ((const float4*)(src + i))[0];
  float4 b = ((const float4*)(src + i))[1];
  bf16x8 o;
  o[0] = (bf16)a.x; o[1] = (bf16)a.y; o[2] = (bf16)a.z; o[3] = (bf16)a.w;
  o[4] = (bf16)b.x; o[5] = (bf16)b.y; o[6] = (bf16)b.z; o[7] = (bf16)b.w;
  *(bf16x8*)(dst + i) = o;
}

// fused conversion of the four 1024x1024 weights into one contiguous dst
__global__ __launch_bounds__(256) void cvt4_kernel(
    const float* __restrict__ s0, const float* __restrict__ s1,
    const float* __restrict__ s2, const float* __restrict__ s3,
    bf16* __restrict__ dst) {
  int seg = blockIdx.x >> 9;
  int blk = blockIdx.x & 511;
  const float* s = (seg == 0) ? s0 : (seg == 1) ? s1 : (seg == 2) ? s2 : s3;
  int i = (blk * 256 + threadIdx.x) * 8;
  float4 a = ((const float4*)(s + i))[0];
  float4 b = ((const float4*)(s + i))[1];
  bf16x8 o;
  o[0] = (bf16)a.x; o[1] = (bf16)a.y; o[2] = (bf16)a.z; o[3] = (bf16)a.w;
  o[4] = (bf16)b.x; o[5] = (bf16)b.y; o[6] = (bf16)b.z; o[7] = (bf16)b.w;
  *(bf16x8*)(dst + seg * 1048576 + i) = o;
}

// ---------------------------------------------------------------------------
// mod = silu(conditioning) @ Wc^T + bc   -> f32 (B, 2E)
// ---------------------------------------------------------------------------
__global__ __launch_bounds__(256) void mod_kernel(
    const float* __restrict__ cond, const float* __restrict__ Wc,
    const float* __restrict__ bc, float* __restrict__ mod) {
  __shared__ float scond[NC];
  int b  = blockIdx.x >> 3;
  int j0 = (blockIdx.x & 7) * 256;
  float c = cond[b * NC + threadIdx.x];
  scond[threadIdx.x] = c / (1.f + __expf(-c));
  __syncthreads();
  int j = j0 + threadIdx.x;
  float acc = bc[j];
  const float* wrow = Wc + (size_t)j * NC;
  for (int cc = 0; cc < NC; ++cc) acc += scond[cc] * wrow[cc];
  mod[b * 2 * NE + j] = acc;
}

// ---------------------------------------------------------------------------
// 128x128 LDS-staged NT GEMM (m97 structure). K multiple of 32.
// MODE 0: fused QKV (N=3072, weight picked by n>>10), scatter epilogue.
// MODE 1: O-projection, f32 row-major out, N=1024.
// ---------------------------------------------------------------------------
template<int MODE>
__global__ __launch_bounds__(256) void gemm128(
    const bf16* __restrict__ A, const bf16* __restrict__ W0,
    const bf16* __restrict__ W1, const bf16* __restrict__ W2,
    void* __restrict__ out, int K) {
  __shared__ bf16 As[128 * 32];
  __shared__ bf16 Bs[128 * 32];
  const int t = threadIdx.x, w = t >> 6, l = t & 63;
  const int lr = l & 15, lg = l >> 4;
  const int wm = w >> 1, wn = w & 1;
  const int m0 = blockIdx.x * 128;
  const int ng = blockIdx.y * 128;

  const bf16* Bw;
  if (MODE == 0) {
    const bf16* Ws[3] = {W0, W1, W2};
    Bw = Ws[ng >> 10] + (size_t)(ng & 1023) * K;
  } else {
    Bw = W0 + (size_t)ng * K;
  }

  f32x4 acc[4][4];
#pragma unroll
  for (int i = 0; i < 4; ++i)
#pragma unroll
    for (int j = 0; j < 4; ++j) acc[i][j] = (f32x4){0.f, 0.f, 0.f, 0.f};

  const int srow = (l >> 2);
  const int scol = (l & 3) * 8;

  for (int kt = 0; kt < K; kt += 32) {
#pragma unroll
    for (int r = 0; r < 2; ++r) {
      int cc = w * 2 + r;
      int row = cc * 16 + srow;
      gload16((char*)As + cc * 1024, A  + (size_t)(m0 + row) * K + kt + scol);
      gload16((char*)Bs + cc * 1024, Bw + (size_t)row        * K + kt + scol);
    }
    __syncthreads();
    bf16x8 af[4], bfr[4];
#pragma unroll
    for (int i = 0; i < 4; ++i) {
      af[i]  = *(const bf16x8*)(As + (wm * 64 + i * 16 + lr) * 32 + lg * 8);
      bfr[i] = *(const bf16x8*)(Bs + (wn * 64 + i * 16 + lr) * 32 + lg * 8);
    }
#pragma unroll
    for (int i = 0; i < 4; ++i)
#pragma unroll
      for (int j = 0; j < 4; ++j)
        acc[i][j] = __builtin_amdgcn_mfma_f32_16x16x32_bf16(af[i], bfr[j], acc[i][j], 0, 0, 0);
    if (kt + 32 < K) __syncthreads();
  }

#pragma unroll
  for (int i = 0; i < 4; ++i) {
#pragma unroll
    for (int j = 0; j < 4; ++j) {
#pragma unroll
      for (int r = 0; r < 4; ++r) {
        int row = m0 + wm * 64 + i * 16 + lg * 4 + r;
        int col = ng + wn * 64 + j * 16 + lr;
        float v = acc[i][j][r];
        if (MODE == 1) {
          ((float*)out)[(size_t)row * NE + col] = v;
        } else {
          int b = row >> 11, s = row & 2047;
          int wi = col >> 10, nc = col & 1023;
          int h = nc >> 6, d = nc & 63;
          size_t idx;
          if (wi == 2)  // V^T: (B,H,D,S)
            idx = 8388608u + (((size_t)(b * NH + h)) * ND + d) * NS + s;
          else          // Q or K: (B,H,S,D)
            idx = (size_t)wi * 4194304u + (((size_t)(b * NH + h)) * NS + s) * ND + d;
          ((bf16*)out)[idx] = (bf16)v;
        }
      }
    }
  }
}

// ---------------------------------------------------------------------------
// Flash attention, causal. Q,K (B,H,S,D), V^T (B,H,D,S). Out (B,S,E) bf16.
// Wave = 16 q-rows. Each wave processes the complementary tile pair
// (t, 127-t) -> all 4096 waves have equal work; 512 equal blocks, all
// co-resident (2 blocks/CU, 2 waves/SIMD sustained).
// Row-sum folded into MFMA (ones-column); row-max via DPP rotates.
// ---------------------------------------------------------------------------
__global__ __launch_bounds__(256) void attn_kernel(
    const bf16* __restrict__ Q, const bf16* __restrict__ Km,
    const bf16* __restrict__ Vt, bf16* __restrict__ O) {
  __shared__ bf16 pbuf[4][16][72];   // per-wave P^T buffer, padded
  const int l = threadIdx.x & 63, w = threadIdx.x >> 6;
  const int lr = l & 15, lg = l >> 4;
  const int bh = blockIdx.y, b = bh >> 4, h = bh & 15;
  const int tp = blockIdx.x * 4 + w;      // 0..63

  const bf16* Qb = Q  + (size_t)bh * NS * ND;
  const bf16* Kb = Km + (size_t)bh * NS * ND;
  const bf16* Vb = Vt + (size_t)bh * ND * NS;

  bf16x8 ones;
#pragma unroll
  for (int i = 0; i < 8; ++i) ones[i] = (bf16)1.0f;

  const float c = 0.125f * 1.44269504089f;   // scale * log2(e)

  for (int pass = 0; pass < 2; ++pass) {
    const int qbase = (pass ? (127 - tp) : tp) * 16;

    bf16x8 qf0 = *(const bf16x8*)(Qb + (size_t)(qbase + lr) * ND + lg * 8);
    bf16x8 qf1 = *(const bf16x8*)(Qb + (size_t)(qbase + lr) * ND + 32 + lg * 8);

    f32x4 o[4], osum;
#pragma unroll
    for (int dt = 0; dt < 4; ++dt) o[dt] = (f32x4){0.f, 0.f, 0.f, 0.f};
    osum = (f32x4){0.f, 0.f, 0.f, 0.f};
    float mrow[4];
    int qr[4];
#pragma unroll
    for (int r = 0; r < 4; ++r) { mrow[r] = -1e30f; qr[r] = qbase + lg * 4 + r; }

    for (int kv0 = 0; kv0 < qbase + 16; kv0 += 64) {
      // ---- QK^T : 16 q-rows x 64 kv ----
      f32x4 s[4];
#pragma unroll
      for (int nt = 0; nt < 4; ++nt) {
        const bf16* kr = Kb + (size_t)(kv0 + nt * 16 + lr) * ND + lg * 8;
        bf16x8 k0 = *(const bf16x8*)kr;
        bf16x8 k1 = *(const bf16x8*)(kr + 32);
        f32x4 z = (f32x4){0.f, 0.f, 0.f, 0.f};
        z = __builtin_amdgcn_mfma_f32_16x16x32_bf16(qf0, k0, z, 0, 0, 0);
        z = __builtin_amdgcn_mfma_f32_16x16x32_bf16(qf1, k1, z, 0, 0, 0);
        s[nt] = z;
      }
      // ---- scale (log2 domain) + causal mask + row max ----
      const bool edge = (kv0 + 63 > qbase);
      float pm[4];
#pragma unroll
      for (int r = 0; r < 4; ++r) pm[r] = -1e30f;
#pragma unroll
      for (int nt = 0; nt < 4; ++nt) {
        f32x4 v = s[nt] * c;
#pragma unroll
        for (int r = 0; r < 4; ++r) {
          if (edge && (kv0 + nt * 16 + lr > qr[r])) v[r] = -1e30f;
          pm[r] = fmaxf(pm[r], v[r]);
        }
        s[nt] = v;
      }
#pragma unroll
      for (int r = 0; r < 4; ++r) pm[r] = rowmax16(pm[r]);
      // ---- online rescale ----
      float al[4];
#pragma unroll
      for (int r = 0; r < 4; ++r) {
        float nm = fmaxf(mrow[r], pm[r]);
        al[r] = exp2f(mrow[r] - nm);
        mrow[r] = nm;
      }
#pragma unroll
      for (int dt = 0; dt < 4; ++dt)
#pragma unroll
        for (int r = 0; r < 4; ++r) o[dt][r] *= al[r];
#pragma unroll
      for (int r = 0; r < 4; ++r) osum[r] *= al[r];
      // ---- P = exp2(s - m), transpose via wave-private LDS ----
#pragma unroll
      for (int nt = 0; nt < 4; ++nt)
#pragma unroll
        for (int r = 0; r < 4; ++r)
          pbuf[w][lg * 4 + r][nt * 16 + lr] = (bf16)exp2f(s[nt][r] - mrow[r]);
      asm volatile("s_waitcnt lgkmcnt(0)" ::: "memory");
      __builtin_amdgcn_sched_barrier(0);
      bf16x8 pa0 = *(const bf16x8*)(&pbuf[w][lr][lg * 8]);
      bf16x8 pa1 = *(const bf16x8*)(&pbuf[w][lr][32 + lg * 8]);
      // ---- row-sum via ones-operand MFMA ----
      osum = __builtin_amdgcn_mfma_f32_16x16x32_bf16(pa0, ones, osum, 0, 0, 0);
      osum = __builtin_amdgcn_mfma_f32_16x16x32_bf16(pa1, ones, osum, 0, 0, 0);
      // ---- PV ----
#pragma unroll
      for (int dt = 0; dt < 4; ++dt) {
        const bf16* vr = Vb + (size_t)(dt * 16 + lr) * NS + kv0 + lg * 8;
        bf16x8 v0 = *(const bf16x8*)vr;
        bf16x8 v1 = *(const bf16x8*)(vr + 32);
        o[dt] = __builtin_amdgcn_mfma_f32_16x16x32_bf16(pa0, v0, o[dt], 0, 0, 0);
        o[dt] = __builtin_amdgcn_mfma_f32_16x16x32_bf16(pa1, v1, o[dt], 0, 0, 0);
      }
      __builtin_amdgcn_sched_barrier(0);
    }

    float rl[4];
#pragma unroll
    for (int r = 0; r < 4; ++r) rl[r] = 1.f / osum[r];
#pragma unroll
    for (int dt = 0; dt < 4; ++dt)
#pragma unroll
      for (int r = 0; r < 4; ++r)
        O[((size_t)(b * NS) + qr[r]) * NE + h * ND + dt * 16 + lr] =
            (bf16)(o[dt][r] * rl[r]);
  }
}

// ---------------------------------------------------------------------------
// RMSNorm + FiLM
// ---------------------------------------------------------------------------
__global__ __launch_bounds__(256) void norm_kernel(
    const float* __restrict__ tmp, const float* __restrict__ rms_scale,
    const float* __restrict__ mod, float* __restrict__ out) {
  int row = blockIdx.x;
  int b = row >> 11;
  const float* trow = tmp + (size_t)row * NE;
  float4 v = ((const float4*)trow)[threadIdx.x];
  float vv[4] = {v.x, v.y, v.z, v.w};
  float ss = vv[0]*vv[0] + vv[1]*vv[1] + vv[2]*vv[2] + vv[3]*vv[3];
#pragma unroll
  for (int mk = 1; mk < 64; mk <<= 1) ss += __shfl_xor(ss, mk, 64);
  __shared__ float sred[4];
  if ((threadIdx.x & 63) == 0) sred[threadIdx.x >> 6] = ss;
  __syncthreads();
  float tot = sred[0] + sred[1] + sred[2] + sred[3];
  float rinv = rsqrtf(tot * (1.f / NE) + 1e-6f);
  const float* modb = mod + b * 2 * NE;
#pragma unroll
  for (int j = 0; j < 4; ++j) {
    int e = threadIdx.x * 4 + j;
    float xn = vv[j] * rinv * rms_scale[e];
    xn = xn * (1.f + modb[NE + e]) + modb[e];
    out[(size_t)row * NE + e] = xn;
  }
}

// ---------------------------------------------------------------------------
extern "C" void kernel_launch(void* const* d_in, const int* in_sizes, int n_in,
                              void* d_out, int out_size, void* d_ws, size_t ws_size,
                              hipStream_t stream) {
  const float* x    = (const float*)d_in[0];
  const float* cond = (const float*)d_in[2];
  const float* Wq   = (const float*)d_in[3];
  const float* Wk   = (const float*)d_in[4];
  const float* Wv   = (const float*)d_in[5];
  const float* Wo   = (const float*)d_in[6];
  const float* rmss = (const float*)d_in[7];
  const float* Wc   = (const float*)d_in[8];
  const float* bc   = (const float*)d_in[9];
  float* out = (float*)d_out;

  char* ws = (char*)d_ws;
  const size_t MB = 1u << 20;
  bf16*  xb  = (bf16*)(ws);               // 0..8MB    (B,S,E) bf16
  bf16*  Wqb = (bf16*)(ws + 8  * MB);     // Wq,Wk,Wv,Wo contiguous 8..16MB
  bf16*  Wkb = (bf16*)(ws + 10 * MB);
  bf16*  Wvb = (bf16*)(ws + 12 * MB);
  bf16*  Wob = (bf16*)(ws + 14 * MB);
  bf16*  Qb  = (bf16*)(ws + 16 * MB);     // (B,H,S,D); K at +4M el; V^T at +8M el
  bf16*  Kb  = (bf16*)(ws + 24 * MB);
  bf16*  Vt  = (bf16*)(ws + 32 * MB);
  bf16*  Oa  = (bf16*)(ws);               // reuse x region
  float* tmp = (float*)(ws + 16 * MB);    // reuse Q/K region
  float* mod = (float*)(ws + 40 * MB);

  const int NX = NB * NS * NE;

  mod_kernel<<<16, 256, 0, stream>>>(cond, Wc, bc, mod);

  cvt_kernel<<<NX / 2048, 256, 0, stream>>>(x, xb, NX);
  cvt4_kernel<<<2048, 256, 0, stream>>>(Wq, Wk, Wv, Wo, Wqb);

  // fused QKV projection: N = 3072
  gemm128<0><<<dim3(32, 24), 256, 0, stream>>>(xb, Wqb, Wkb, Wvb, Qb, NE);

  attn_kernel<<<dim3(16, 32), 256, 0, stream>>>(Qb, Kb, Vt, Oa);

  // O projection -> f32 tmp
  gemm128<1><<<dim3(32, 8), 256, 0, stream>>>(Oa, Wob, nullptr, nullptr, tmp, NE);

  norm_kernel<<<NB * NS, 256, 0, stream>>>(tmp, rmss, mod, out);
}